// Round 7
// baseline (271.932 us; speedup 1.0000x reference)
//
#include <hip/hip_runtime.h>
#include <hip/hip_bf16.h>

// HierarchicalMambaBlock: B=2,T=1024,DIM=512 -> D_INNER=1024, DT_RANK=64, D_STATE=16
// GEMMs on MFMA via split precision (hi/lo bf16, 3 MFMAs: Ah*Bh + Al*Bh + Ah*Bl).
// Split operands stored INTERLEAVED: each 4-f32 group -> [hi0..hi3|lo0..lo3].
// Round-7 = round-6 + TWO producer kernels that kill the 16x-redundant
// A-staging found by rocprof in P9 (43us, VALUBusy 28%: silu+split recomputed
// per n-block) and P8 (CTX average recomputed per (n,z)-block):
//   ctx_kernel:       ctxi = split((y0+up(y1)+up(y2))/3)      [P8 -> AMODE=0]
//   combine_h1_kernel: h1i = split(silu(h1p0+h1p1))           [P9 -> AMODE=0]
// Same split2/expression order as the old inline paths -> bit-identical.
#define BATCH   2
#define SEQ     1024
#define DIMSZ   512
#define DINNER  1024
#define DTRANK  64
#define DSTATE  16
#define CHUNK   32

typedef __hip_bfloat16 bf16;
typedef __attribute__((ext_vector_type(8))) short s8v;   // 8 bf16 MFMA frag
typedef __attribute__((ext_vector_type(4))) float f4v;   // 4 f32 acc

// Interleaved bf16 split-workspace offsets (bf16 elements, relative to bws).
constexpr size_t OXI   = 0;          // x           2048x512   -> 2,097,152
constexpr size_t OIPI  = 2097152;    // in_proj_w   2048x512   -> 2,097,152
constexpr size_t OXWI  = 4194304;    // xproj_w     3x96x1024  ->   589,824
constexpr size_t ODTI  = 4784128;    // dtproj_w    3x1024x64  ->   393,216
constexpr size_t OC1I  = 5177344;    // cg_w1       512x1024   -> 1,048,576
constexpr size_t OC2I  = 6225920;    // cg_w2       1024x512   -> 1,048,576
constexpr size_t OOPI  = 7274496;    // out_proj_w  512x1024   -> 1,048,576
constexpr size_t OPJI  = 8323072;    // pj dt-cols  3584x64    ->   458,752
constexpr size_t OFGI  = 10878976;   // fusedg      2048x1024  -> 4,194,304
constexpr size_t OCTXI = 15073280;   // ctx         2048x1024  -> 4,194,304
constexpr size_t OH1I  = 19267584;   // h1          2048x512   -> 2,097,152
// end: 21,364,736 bf16 = 42.7 MB; f32 region 95.6 MB; total ~138 MB < ws

constexpr size_t PJP_STRIDE = 344064;   // 3584 x 96 per split-K partial

__device__ __forceinline__ float sigmoidf_(float x) { return 1.f / (1.f + __expf(-x)); }
__device__ __forceinline__ float siluf_(float x) { return x * sigmoidf_(x); }
__device__ __forceinline__ void split2(float v, bf16& hi, bf16& lo) {
    hi = __float2bfloat16(v);
    lo = __float2bfloat16(v - __bfloat162float(hi));
}
// interleaved store: 4 f32 -> [hi4|lo4] (16 B) at p
__device__ __forceinline__ void split_store4i(const float4 v, bf16* __restrict__ p) {
    union { bf16 b[8]; uint4 q; } U;
    split2(v.x, U.b[0], U.b[4]); split2(v.y, U.b[1], U.b[5]);
    split2(v.z, U.b[2], U.b[6]); split2(v.w, U.b[3], U.b[7]);
    *reinterpret_cast<uint4*>(p) = U.q;
}
// LDS-stage split: 4 f32 -> separate hi/lo uint2 stores (inline-split paths)
__device__ __forceinline__ void split_store4(const float4 v,
                                             bf16* __restrict__ ph,
                                             bf16* __restrict__ pl) {
    union { bf16 b[4]; uint2 u; } H, L;
    split2(v.x, H.b[0], L.b[0]); split2(v.y, H.b[1], L.b[1]);
    split2(v.z, H.b[2], L.b[2]); split2(v.w, H.b[3], L.b[3]);
    *reinterpret_cast<uint2*>(ph) = H.u;
    *reinterpret_cast<uint2*>(pl) = L.u;
}

// ---------------------------------------------------------------------------
// Prologue: split x + all weights into persistent interleaved bf16 hi/lo.
// ---------------------------------------------------------------------------
__global__ void split_inputs_kernel(
    const float* __restrict__ x,   const float* __restrict__ ipw,
    const float* __restrict__ xw,  const float* __restrict__ dtw,
    const float* __restrict__ c1,  const float* __restrict__ c2,
    const float* __restrict__ opw, bf16* __restrict__ bws)
{
    int blk = blockIdx.x;
    const float* src; size_t off;
    if (blk < 1024)      { src = x;   off = OXI;  }
    else if (blk < 2048) { src = ipw; off = OIPI; blk -= 1024; }
    else if (blk < 2336) { src = xw;  off = OXWI; blk -= 2048; }
    else if (blk < 2528) { src = dtw; off = ODTI; blk -= 2336; }
    else if (blk < 3040) { src = c1;  off = OC1I; blk -= 2528; }
    else if (blk < 3552) { src = c2;  off = OC2I; blk -= 3040; }
    else                 { src = opw; off = OOPI; blk -= 3552; }
    int i = blk * 1024 + threadIdx.x * 4;
    float4 v = *reinterpret_cast<const float4*>(src + i);
    split_store4i(v, bws + off + (size_t)i * 2);
}

// ---------------------------------------------------------------------------
// MFMA GEMM, 64x64 tile, BK=64, 4 waves, register prefetch, optional SPLIT-K
// via gridDim.z (each z-block covers K cols [z*K, z*K+K) and writes its own
// C partial at z * gridDim.x*64 * N).
// AMODE: 0 = interleaved pre-split A (pure-copy staging)
//        1 = CTX: A = (y0 + up(y1) + up(y2))/3, f32 inline split   [unused]
//        2 = SUM2+SILU: A = silu(sa0 + sa1), f32 inline split      [unused]
// ACT: 0 none, 1 silu, 2 sigmoid, 3 bias+softplus
// DT_MODE: stacked dtproj: per-block W/bias select by scale
// GATE3:   v = softmax_fused(y0,y1,y2,sw)[gm,gn] * v * silu(xz gate)
// OUT_SPLIT: write interleaved hi/lo bf16 (Ci) instead of f32 C.
// ---------------------------------------------------------------------------
template <int ACT, bool ADD_RES, bool DT_MODE, int AMODE, bool GATE3, bool OUT_SPLIT>
__global__ __launch_bounds__(256) void mgemm_kernel(
    const bf16* __restrict__ Ai, int lda, int K, int ldb,
    const bf16* __restrict__ Bi,
    const float* __restrict__ bias,
    const float* __restrict__ res,          // residual (ADD_RES, z==0 only)
    const float* __restrict__ gxz,          // xz (GATE3)
    const float* __restrict__ yy0,          // AMODE1 / GATE3 (y per scale)
    const float* __restrict__ yy1,
    const float* __restrict__ yy2,
    const float* __restrict__ sa0,          // AMODE2 partials
    const float* __restrict__ sa1,
    const float* __restrict__ swp,          // GATE3 softmax weights (3)
    float* __restrict__ C, bf16* __restrict__ Ci, int N)
{
    __shared__ bf16 Ah[64][72], Al[64][72], Bh[64][72], Bl[64][72];

    const int m0 = blockIdx.x * 64;
    const int n0 = blockIdx.y * 64;
    const int kz = blockIdx.z;
    const int koff = kz * K;
    const size_t coff = (size_t)kz * (size_t)(gridDim.x * 64) * N;
    const int tid = threadIdx.x;
    const int wave = tid >> 6;
    const int lane = tid & 63;
    const int wm = (wave >> 1) * 32;
    const int wn = (wave & 1) * 32;
    const int m16 = lane & 15;
    const int q   = lane >> 4;

    int scale = 0;
    if (DT_MODE) scale = (m0 < 2048) ? 0 : ((m0 < 3072) ? 1 : 2);
    const bf16* Bip = DT_MODE ? (Bi + (size_t)scale * 1024 * ldb * 2) : Bi;
    const float* bias_p = (ACT == 3) ? (DT_MODE ? bias + (size_t)scale * N : bias) : nullptr;

    f4v acc[2][2];
#pragma unroll
    for (int i = 0; i < 2; i++)
#pragma unroll
        for (int j = 0; j < 2; j++)
#pragma unroll
            for (int r = 0; r < 4; r++) acc[i][j][r] = 0.f;

    const int cch = tid & 15;
    const int c4  = cch * 4;
    const int r0  = tid >> 4;

    // A row pointers
    const float* a0p[4]; const float* a1p[4]; const float* a2p[4];
    const float* s0p[4]; const float* s1p[4];
    const bf16*  aip[4];
#pragma unroll
    for (int p = 0; p < 4; p++) {
        int m = m0 + r0 + p * 16;
        if (AMODE == 1) {
            int b = m >> 10, t = m & 1023;
            a0p[p] = yy0 + koff + (size_t)m * 1024 + c4;
            a1p[p] = yy1 + koff + (size_t)((b << 9) + (t >> 1)) * 1024 + c4;
            a2p[p] = yy2 + koff + (size_t)((b << 8) + (t >> 2)) * 1024 + c4;
        } else if (AMODE == 2) {
            s0p[p] = sa0 + koff + (size_t)m * lda + c4;
            s1p[p] = sa1 + koff + (size_t)m * lda + c4;
        } else {
            aip[p] = Ai + ((size_t)m * lda + koff + c4) * 2;
        }
    }
    const bf16* Bi_b = Bip + ((size_t)(n0 + r0) * ldb + koff + c4) * 2;

    const int nkt = K >> 6;
    float4 raf[4]; uint2 rah[4], ral[4], rbh[4], rbl[4];
#pragma unroll
    for (int p = 0; p < 4; p++) {
        if (AMODE == 1) {
            float4 u = *reinterpret_cast<const float4*>(a0p[p]);
            float4 v = *reinterpret_cast<const float4*>(a1p[p]);
            float4 w = *reinterpret_cast<const float4*>(a2p[p]);
            raf[p] = make_float4((u.x + v.x + w.x) * (1.f / 3.f), (u.y + v.y + w.y) * (1.f / 3.f),
                                 (u.z + v.z + w.z) * (1.f / 3.f), (u.w + v.w + w.w) * (1.f / 3.f));
        } else if (AMODE == 2) {
            float4 u = *reinterpret_cast<const float4*>(s0p[p]);
            float4 v = *reinterpret_cast<const float4*>(s1p[p]);
            raf[p] = make_float4(siluf_(u.x + v.x), siluf_(u.y + v.y),
                                 siluf_(u.z + v.z), siluf_(u.w + v.w));
        } else {
            uint4 ua = *reinterpret_cast<const uint4*>(aip[p]);
            rah[p] = make_uint2(ua.x, ua.y); ral[p] = make_uint2(ua.z, ua.w);
        }
        uint4 ub = *reinterpret_cast<const uint4*>(Bi_b + (size_t)(p * 16) * ldb * 2);
        rbh[p] = make_uint2(ub.x, ub.y); rbl[p] = make_uint2(ub.z, ub.w);
    }

    for (int kt = 0; kt < nkt; kt++) {
        if (kt) __syncthreads();
#pragma unroll
        for (int p = 0; p < 4; p++) {
            int r = r0 + p * 16;
            if (AMODE != 0) {
                split_store4(raf[p], &Ah[r][c4], &Al[r][c4]);
            } else {
                *reinterpret_cast<uint2*>(&Ah[r][c4]) = rah[p];
                *reinterpret_cast<uint2*>(&Al[r][c4]) = ral[p];
            }
            *reinterpret_cast<uint2*>(&Bh[r][c4]) = rbh[p];
            *reinterpret_cast<uint2*>(&Bl[r][c4]) = rbl[p];
        }
        __syncthreads();
        if (kt + 1 < nkt) {
            int off = (kt + 1) * 64;
#pragma unroll
            for (int p = 0; p < 4; p++) {
                if (AMODE == 1) {
                    float4 u = *reinterpret_cast<const float4*>(a0p[p] + off);
                    float4 v = *reinterpret_cast<const float4*>(a1p[p] + off);
                    float4 w = *reinterpret_cast<const float4*>(a2p[p] + off);
                    raf[p] = make_float4((u.x + v.x + w.x) * (1.f / 3.f), (u.y + v.y + w.y) * (1.f / 3.f),
                                         (u.z + v.z + w.z) * (1.f / 3.f), (u.w + v.w + w.w) * (1.f / 3.f));
                } else if (AMODE == 2) {
                    float4 u = *reinterpret_cast<const float4*>(s0p[p] + off);
                    float4 v = *reinterpret_cast<const float4*>(s1p[p] + off);
                    raf[p] = make_float4(siluf_(u.x + v.x), siluf_(u.y + v.y),
                                         siluf_(u.z + v.z), siluf_(u.w + v.w));
                } else {
                    uint4 ua = *reinterpret_cast<const uint4*>(aip[p] + (size_t)off * 2);
                    rah[p] = make_uint2(ua.x, ua.y); ral[p] = make_uint2(ua.z, ua.w);
                }
                uint4 ub = *reinterpret_cast<const uint4*>(Bi_b + ((size_t)(p * 16) * ldb + off) * 2);
                rbh[p] = make_uint2(ub.x, ub.y); rbl[p] = make_uint2(ub.z, ub.w);
            }
        }
#pragma unroll
        for (int kk = 0; kk < 2; kk++) {
            const int col = kk * 32 + q * 8;
            s8v ah[2], al[2], bh[2], bl[2];
#pragma unroll
            for (int i = 0; i < 2; i++) {
                int ar = wm + i * 16 + m16;
                ah[i] = *reinterpret_cast<const s8v*>(&Ah[ar][col]);
                al[i] = *reinterpret_cast<const s8v*>(&Al[ar][col]);
                int br = wn + i * 16 + m16;
                bh[i] = *reinterpret_cast<const s8v*>(&Bh[br][col]);
                bl[i] = *reinterpret_cast<const s8v*>(&Bl[br][col]);
            }
#pragma unroll
            for (int i = 0; i < 2; i++)
#pragma unroll
                for (int j = 0; j < 2; j++) {
                    acc[i][j] = __builtin_amdgcn_mfma_f32_16x16x32_bf16(ah[i], bh[j], acc[i][j], 0, 0, 0);
                    acc[i][j] = __builtin_amdgcn_mfma_f32_16x16x32_bf16(al[i], bh[j], acc[i][j], 0, 0, 0);
                    acc[i][j] = __builtin_amdgcn_mfma_f32_16x16x32_bf16(ah[i], bl[j], acc[i][j], 0, 0, 0);
                }
        }
    }

    // GATE3 softmax weights
    float e0 = 0.f, e1 = 0.f, e2 = 0.f, inv = 0.f;
    if (GATE3) {
        float s0 = swp[0], s1 = swp[1], s2 = swp[2];
        float mx = fmaxf(s0, fmaxf(s1, s2));
        e0 = __expf(s0 - mx); e1 = __expf(s1 - mx); e2 = __expf(s2 - mx);
        inv = 1.f / (e0 + e1 + e2);
    }

    // Epilogue. D mapping (verified): row = q*4 + reg, col = lane&15.
#pragma unroll
    for (int i = 0; i < 2; i++) {
#pragma unroll
        for (int j = 0; j < 2; j++) {
#pragma unroll
            for (int r = 0; r < 4; r++) {
                int gm = m0 + wm + i * 16 + q * 4 + r;
                int gn = n0 + wn + j * 16 + m16;
                float v = acc[i][j][r];
                if (ACT == 3) { v += bias_p[gn]; v = (v > 20.f) ? v : __logf(1.f + __expf(v)); }
                else if (ACT == 1) v = siluf_(v);
                else if (ACT == 2) v = sigmoidf_(v);
                if (GATE3) {
                    int b = gm >> 10, t = gm & 1023;
                    float f = (e0 * yy0[(size_t)gm * 1024 + gn]
                             + e1 * yy1[(size_t)((b << 9) + (t >> 1)) * 1024 + gn]
                             + e2 * yy2[(size_t)((b << 8) + (t >> 2)) * 1024 + gn]) * inv;
                    v = f * v * siluf_(gxz[(size_t)gm * 2048 + 1024 + gn]);
                } else if (ADD_RES) {
                    if (kz == 0) v += res[(size_t)gm * N + gn];
                }
                if (OUT_SPLIT) {
                    bf16 hh, ll; split2(v, hh, ll);
                    size_t gb = ((size_t)gm * N + (gn & ~3)) * 2 + (gn & 3);
                    Ci[gb] = hh;
                    Ci[gb + 4] = ll;
                } else {
                    C[coff + (size_t)gm * N + gn] = v;
                }
            }
        }
    }
}

// ---------------------------------------------------------------------------
// xproj MFMA: stacked M=3584, N=96 (clamped), K=1024 SPLIT-K4 (z in {0..3},
// 256 cols each). Grid (56,2,4) = 448 blocks. Writes f32 partial pjp[z].
// ---------------------------------------------------------------------------
__global__ __launch_bounds__(256) void xproj_mfma_kernel(
    const float* __restrict__ A,
    const bf16* __restrict__ xwi,
    float* __restrict__ pjp)
{
    __shared__ bf16 Ah[64][72], Al[64][72], Bh[64][72], Bl[64][72];

    const int m0 = blockIdx.x * 64;
    const int n0 = blockIdx.y * 64;
    const int kz = blockIdx.z;
    const int koff = kz * 256;
    const int tid = threadIdx.x;
    const int wave = tid >> 6;
    const int lane = tid & 63;
    const int wm = (wave >> 1) * 32;
    const int wn = (wave & 1) * 32;
    const int m16 = lane & 15;
    const int q   = lane >> 4;

    const int scale = (m0 < 2048) ? 0 : ((m0 < 3072) ? 1 : 2);
    const bf16* Bip = xwi + (size_t)scale * 96 * 1024 * 2;

    f4v acc[2][2];
#pragma unroll
    for (int i = 0; i < 2; i++)
#pragma unroll
        for (int j = 0; j < 2; j++)
#pragma unroll
            for (int r = 0; r < 4; r++) acc[i][j][r] = 0.f;

    const int cch = tid & 15;
    const int c4  = cch * 4;
    const int r0  = tid >> 4;

    const float* Abase = A + (size_t)(m0 + r0) * 1024 + koff + c4;
    const bf16* Bi_b = Bip + ((size_t)(n0 + r0) * 1024 + koff + c4) * 2;
    bool bok[4];
#pragma unroll
    for (int p = 0; p < 4; p++) bok[p] = (n0 + r0 + p * 16) < 96;

    const int nkt = 4;   // 256 / 64
    float4 ra[4]; uint2 rbh[4], rbl[4];
#pragma unroll
    for (int p = 0; p < 4; p++) {
        ra[p] = *reinterpret_cast<const float4*>(Abase + (size_t)(p * 16) * 1024);
        if (bok[p]) {
            uint4 ub = *reinterpret_cast<const uint4*>(Bi_b + (size_t)(p * 16) * 1024 * 2);
            rbh[p] = make_uint2(ub.x, ub.y); rbl[p] = make_uint2(ub.z, ub.w);
        } else { rbh[p] = make_uint2(0u, 0u); rbl[p] = make_uint2(0u, 0u); }
    }

    for (int kt = 0; kt < nkt; kt++) {
        if (kt) __syncthreads();
#pragma unroll
        for (int p = 0; p < 4; p++) {
            int r = r0 + p * 16;
            split_store4(ra[p], &Ah[r][c4], &Al[r][c4]);
            *reinterpret_cast<uint2*>(&Bh[r][c4]) = rbh[p];
            *reinterpret_cast<uint2*>(&Bl[r][c4]) = rbl[p];
        }
        __syncthreads();
        if (kt + 1 < nkt) {
            int off = (kt + 1) * 64;
#pragma unroll
            for (int p = 0; p < 4; p++) {
                ra[p] = *reinterpret_cast<const float4*>(Abase + off + (size_t)(p * 16) * 1024);
                if (bok[p]) {
                    uint4 ub = *reinterpret_cast<const uint4*>(Bi_b + ((size_t)(p * 16) * 1024 + off) * 2);
                    rbh[p] = make_uint2(ub.x, ub.y); rbl[p] = make_uint2(ub.z, ub.w);
                }
            }
        }
#pragma unroll
        for (int kk = 0; kk < 2; kk++) {
            const int col = kk * 32 + q * 8;
            s8v ah[2], al[2], bh[2], bl[2];
#pragma unroll
            for (int i = 0; i < 2; i++) {
                int ar = wm + i * 16 + m16;
                ah[i] = *reinterpret_cast<const s8v*>(&Ah[ar][col]);
                al[i] = *reinterpret_cast<const s8v*>(&Al[ar][col]);
                int br = wn + i * 16 + m16;
                bh[i] = *reinterpret_cast<const s8v*>(&Bh[br][col]);
                bl[i] = *reinterpret_cast<const s8v*>(&Bl[br][col]);
            }
#pragma unroll
            for (int i = 0; i < 2; i++)
#pragma unroll
                for (int j = 0; j < 2; j++) {
                    acc[i][j] = __builtin_amdgcn_mfma_f32_16x16x32_bf16(ah[i], bh[j], acc[i][j], 0, 0, 0);
                    acc[i][j] = __builtin_amdgcn_mfma_f32_16x16x32_bf16(al[i], bh[j], acc[i][j], 0, 0, 0);
                    acc[i][j] = __builtin_amdgcn_mfma_f32_16x16x32_bf16(ah[i], bl[j], acc[i][j], 0, 0, 0);
                }
        }
    }

    float* out = pjp + (size_t)kz * PJP_STRIDE;
#pragma unroll
    for (int i = 0; i < 2; i++) {
#pragma unroll
        for (int j = 0; j < 2; j++) {
            int gn = n0 + wn + j * 16 + m16;
            if (gn >= 96) continue;
#pragma unroll
            for (int r = 0; r < 4; r++) {
                int gm = m0 + wm + i * 16 + q * 4 + r;
                out[(size_t)gm * 96 + gn] = acc[i][j][r];
            }
        }
    }
}

// ---------------------------------------------------------------------------
// combine_pj: pj = pjp0+pjp1+pjp2+pjp3 (3584x96); dt cols (gn<64) also
// emitted as interleaved split for dtproj. 336 blocks x 256 threads x 4.
// ---------------------------------------------------------------------------
__global__ void combine_pj_kernel(const float* __restrict__ pjp,
                                  float* __restrict__ pj,
                                  bf16* __restrict__ pjdti)
{
    int g = blockIdx.x * 256 + threadIdx.x;   // 86016 float4 groups
    if (g >= 86016) return;
    int gm = g / 24;
    int gc = (g % 24) * 4;
    size_t o = (size_t)gm * 96 + gc;
    float4 a = *reinterpret_cast<const float4*>(pjp + o);
    float4 b = *reinterpret_cast<const float4*>(pjp + PJP_STRIDE + o);
    float4 c = *reinterpret_cast<const float4*>(pjp + 2 * PJP_STRIDE + o);
    float4 d = *reinterpret_cast<const float4*>(pjp + 3 * PJP_STRIDE + o);
    float4 s = make_float4(a.x + b.x + c.x + d.x, a.y + b.y + c.y + d.y,
                           a.z + b.z + c.z + d.z, a.w + b.w + c.w + d.w);
    *reinterpret_cast<float4*>(pj + o) = s;
    if (gc < 64) split_store4i(s, pjdti + ((size_t)gm * 64 + gc) * 2);
}

// ---------------------------------------------------------------------------
// ctx: ctxi = split((y0 + up(y1) + up(y2)) / 3). 2048 blocks x 256 x 4 elems.
// Same f32 expression order as the old AMODE=1 inline path -> bit-identical.
// ---------------------------------------------------------------------------
__global__ void ctx_kernel(const float* __restrict__ y0,
                           const float* __restrict__ y1,
                           const float* __restrict__ y2,
                           bf16* __restrict__ ctxi)
{
    int g = blockIdx.x * 256 + threadIdx.x;   // 524,288 float4 groups
    int m = g >> 8;
    int k = (g & 255) << 2;
    int b = m >> 10, t = m & 1023;
    float4 u = *reinterpret_cast<const float4*>(y0 + (size_t)m * 1024 + k);
    float4 v = *reinterpret_cast<const float4*>(y1 + (size_t)((b << 9) + (t >> 1)) * 1024 + k);
    float4 w = *reinterpret_cast<const float4*>(y2 + (size_t)((b << 8) + (t >> 2)) * 1024 + k);
    float4 c = make_float4((u.x + v.x + w.x) * (1.f / 3.f), (u.y + v.y + w.y) * (1.f / 3.f),
                           (u.z + v.z + w.z) * (1.f / 3.f), (u.w + v.w + w.w) * (1.f / 3.f));
    split_store4i(c, ctxi + ((size_t)m * 1024 + k) * 2);
}

// ---------------------------------------------------------------------------
// combine_h1: h1i = split(silu(h1p0 + h1p1)). 1024 blocks x 256 x 4 elems.
// Same f32 expression order as the old AMODE=2 inline path -> bit-identical.
// ---------------------------------------------------------------------------
__global__ void combine_h1_kernel(const float* __restrict__ h1p,
                                  bf16* __restrict__ h1i)
{
    int g = blockIdx.x * 256 + threadIdx.x;   // 262,144 float4 groups
    size_t o = (size_t)g * 4;
    float4 u = *reinterpret_cast<const float4*>(h1p + o);
    float4 v = *reinterpret_cast<const float4*>(h1p + 1048576 + o);
    float4 s = make_float4(siluf_(u.x + v.x), siluf_(u.y + v.y),
                           siluf_(u.z + v.z), siluf_(u.w + v.w));
    split_store4i(s, h1i + o * 2);
}

// ---------------------------------------------------------------------------
// Fused downsample + depthwise causal conv(K=4) + bias + SiLU, all 3 scales.
// ---------------------------------------------------------------------------
__global__ void conv_fused_kernel(const float* __restrict__ xz,
                                  const float* __restrict__ cw,
                                  const float* __restrict__ cb,
                                  float* __restrict__ xc)
{
    int idx = blockIdx.x * blockDim.x + threadIdx.x;
    if (idx >= 3670016) return;
    int s, rel;
    if (idx < 2097152)      { s = 0; rel = idx; }
    else if (idx < 3145728) { s = 1; rel = idx - 2097152; }
    else                    { s = 2; rel = idx - 3145728; }
    int c = rel & 1023;
    int row = rel >> 10;
    int Ts = 1024 >> s;
    int b = row / Ts;
    int t = row - b * Ts;
    const float* base = xz + (size_t)(b * 1024) * 2048 + c;

    float acc = cb[s * 1024 + c];
#pragma unroll
    for (int k = 0; k < 4; k++) {
        int tau = t - 3 + k;
        if (tau < 0) continue;
        float xv;
        if (s == 0) {
            xv = base[(size_t)tau * 2048];
        } else if (s == 1) {
            xv = 0.5f * (base[(size_t)(2 * tau) * 2048] + base[(size_t)(2 * tau + 1) * 2048]);
        } else {
            xv = 0.25f * (base[(size_t)(4 * tau) * 2048] + base[(size_t)(4 * tau + 1) * 2048]
                        + base[(size_t)(4 * tau + 2) * 2048] + base[(size_t)(4 * tau + 3) * 2048]);
        }
        acc = fmaf(cw[(s * 1024 + c) * 4 + k], xv, acc);
    }
    xc[idx] = siluf_(acc);
}

// ---------------------------------------------------------------------------
// Chunked selective scan. State layout: [s][b][chunk][j][d] (d fastest).
// ---------------------------------------------------------------------------
__device__ __forceinline__ void scan_decode(int blk, int& s, int& nchunk, int& Ts,
                                            int& dquad, int& chunk, int& b, size_t& soff)
{
    int local;
    if (blk < 256)      { s = 0; local = blk;       soff = 0; }
    else if (blk < 384) { s = 1; local = blk - 256; soff = 1048576; }
    else                { s = 2; local = blk - 384; soff = 1572864; }
    nchunk = 32 >> s;
    Ts = 1024 >> s;
    dquad = local & 3;
    chunk = (local >> 2) & (nchunk - 1);
    b = local >> (7 - s);
}

// pass1: per-chunk (prodA, h) states; j-split (8 states/block), 896 blocks.
__global__ __launch_bounds__(256) void scan_pass1(
    const float* __restrict__ dt0, const float* __restrict__ xc0, const float* __restrict__ pj0,
    const float* __restrict__ dt1, const float* __restrict__ xc1, const float* __restrict__ pj1,
    const float* __restrict__ dt2, const float* __restrict__ xc2, const float* __restrict__ pj2,
    const float* __restrict__ A_log,
    float* __restrict__ prodA_buf, float* __restrict__ h_buf)
{
    const int jhalf = (blockIdx.x >= 448) ? 1 : 0;
    const int jo = jhalf * 8;
    int s, nchunk, Ts, dquad, chunk, b; size_t soff;
    scan_decode(blockIdx.x - jhalf * 448, s, nchunk, Ts, dquad, chunk, b, soff);
    const float* dt = (s == 0) ? dt0 : (s == 1) ? dt1 : dt2;
    const float* xc = (s == 0) ? xc0 : (s == 1) ? xc1 : xc2;
    const float* pj = (s == 0) ? pj0 : (s == 1) ? pj1 : pj2;

    const int d = dquad * 256 + threadIdx.x;
    const size_t rowbase = (size_t)b * Ts;
    const int t0 = chunk * CHUNK;

    float Acoef[8], h[8], p[8];
#pragma unroll
    for (int j = 0; j < 8; j++) {
        Acoef[j] = -__expf(A_log[((size_t)(s * DINNER + d)) * 16 + jo + j]);
        h[j] = 0.f; p[j] = 1.f;
    }

    __shared__ float bcB[CHUNK][8];
    if (threadIdx.x < CHUNK * 8) {
        int i = threadIdx.x >> 3, jj = threadIdx.x & 7;
        bcB[i][jj] = pj[(rowbase + t0 + i) * 96 + 64 + jo + jj];
    }
    __syncthreads();

    for (int i = 0; i < CHUNK; i++) {
        size_t t = rowbase + t0 + i;
        float dtv = dt[t * DINNER + d];
        float xv  = xc[t * DINNER + d];
#pragma unroll
        for (int j = 0; j < 8; j++) {
            float dA  = fmaxf(__expf(dtv * Acoef[j]), 1e-38f);
            float dbx = fmaxf(dtv * bcB[i][j] * xv, 1e-38f);
            h[j] = fmaf(dA, h[j], dbx);
            p[j] *= dA;
        }
    }

    size_t base = soff + (size_t)((b * nchunk + chunk) * 16 + jo) * 1024 + d;
#pragma unroll
    for (int j = 0; j < 8; j++) {
        prodA_buf[base + (size_t)j * 1024] = p[j];
        h_buf[base + (size_t)j * 1024] = h[j];
    }
}

// scan_prefix: in-place exclusive prefix over chunks: h_buf[c] <- H_excl(c).
__global__ __launch_bounds__(256) void scan_prefix_kernel(
    const float* __restrict__ prodA_buf, float* __restrict__ h_buf)
{
    int blk = blockIdx.x;
    int s; size_t soff;
    if (blk < 128)      { s = 0; soff = 0; }
    else if (blk < 256) { s = 1; soff = 1048576; blk -= 128; }
    else                { s = 2; soff = 1572864; blk -= 256; }
    const int nchunk = 32 >> s;
    const int b  = blk >> 6;          // local = b*64 + j*4 + dq
    const int j  = (blk >> 2) & 15;
    const int dq = blk & 3;
    const int d  = dq * 256 + threadIdx.x;

    float H = 0.f;
    for (int c = 0; c < nchunk; c++) {
        size_t idx = soff + (size_t)((b * nchunk + c) * 16 + j) * 1024 + d;
        float p = prodA_buf[idx];
        float h = h_buf[idx];
        h_buf[idx] = H;
        H = fmaf(p, H, h);
    }
}

// pass2: unified 16-state, O(1) carry, writes final y directly. 448 blocks.
__global__ __launch_bounds__(256) void scan_pass2(
    const float* __restrict__ dt0, const float* __restrict__ xc0,
    const float* __restrict__ pj0,
    const float* __restrict__ dt1, const float* __restrict__ xc1,
    const float* __restrict__ pj1,
    const float* __restrict__ dt2, const float* __restrict__ xc2,
    const float* __restrict__ pj2,
    float* __restrict__ y0, float* __restrict__ y1, float* __restrict__ y2,
    const float* __restrict__ A_log, const float* __restrict__ D_p,
    const float* __restrict__ carry)
{
    int s, nchunk, Ts, dquad, chunk, b; size_t soff;
    scan_decode(blockIdx.x, s, nchunk, Ts, dquad, chunk, b, soff);
    const float* dt = (s == 0) ? dt0 : (s == 1) ? dt1 : dt2;
    const float* xc = (s == 0) ? xc0 : (s == 1) ? xc1 : xc2;
    const float* pj = (s == 0) ? pj0 : (s == 1) ? pj1 : pj2;
    float* y = (s == 0) ? y0 : (s == 1) ? y1 : y2;

    const int d = dquad * 256 + threadIdx.x;
    const size_t rowbase = (size_t)b * Ts;
    const int t0 = chunk * CHUNK;

    float Acoef[16], h[16];
    const size_t cb = soff + (size_t)((b * nchunk + chunk) * 16) * 1024 + d;
#pragma unroll
    for (int j = 0; j < 16; j++) {
        Acoef[j] = -__expf(A_log[((size_t)(s * DINNER + d)) * 16 + j]);
        h[j] = carry[cb + (size_t)j * 1024];
    }
    const float Dp = D_p[s * DINNER + d];

    __shared__ float bc[CHUNK][32];   // B (0..15) and C (16..31)
    for (int u = threadIdx.x; u < CHUNK * 32; u += 256) {
        int i = u >> 5, jj = u & 31;
        bc[i][jj] = pj[(rowbase + t0 + i) * 96 + 64 + jj];
    }
    __syncthreads();

    for (int i = 0; i < CHUNK; i++) {
        size_t t = rowbase + t0 + i;
        float dtv = dt[t * DINNER + d];
        float xv  = xc[t * DINNER + d];
        float accy = 0.f;
#pragma unroll
        for (int j = 0; j < 16; j++) {
            float dA  = fmaxf(__expf(dtv * Acoef[j]), 1e-38f);
            float dbx = fmaxf(dtv * bc[i][j] * xv, 1e-38f);
            h[j] = fmaf(dA, h[j], dbx);
            accy = fmaf(bc[i][16 + j], h[j], accy);
        }
        y[t * DINNER + d] = accy + Dp * xv;
    }
}

// ---------------------------------------------------------------------------
// LayerNorm over outp0+outp1 (split-K partials of out_proj).
// ---------------------------------------------------------------------------
__global__ __launch_bounds__(256) void ln_kernel(
    const float* __restrict__ ya, const float* __restrict__ yb,
    const float* __restrict__ gamma,
    const float* __restrict__ beta, float* __restrict__ out)
{
    int token = blockIdx.x;
    int tid = threadIdx.x;
    size_t o = (size_t)token * DIMSZ;
    float v0 = ya[o + tid] + yb[o + tid];
    float v1 = ya[o + tid + 256] + yb[o + tid + 256];
    __shared__ float s1[256], s2[256];
    s1[tid] = v0 + v1;
    s2[tid] = v0 * v0 + v1 * v1;
    __syncthreads();
    for (int off = 128; off > 0; off >>= 1) {
        if (tid < off) { s1[tid] += s1[tid + off]; s2[tid] += s2[tid + off]; }
        __syncthreads();
    }
    float mu = s1[0] * (1.f / 512.f);
    float var = s2[0] * (1.f / 512.f) - mu * mu;
    float rstd = rsqrtf(var + 1e-5f);
    float* orow = out + o;
    orow[tid]       = (v0 - mu) * rstd * gamma[tid]       + beta[tid];
    orow[tid + 256] = (v1 - mu) * rstd * gamma[tid + 256] + beta[tid + 256];
}

// ---------------------------------------------------------------------------
extern "C" void kernel_launch(void* const* d_in, const int* in_sizes, int n_in,
                              void* d_out, int out_size, void* d_ws, size_t ws_size,
                              hipStream_t stream)
{
    const float* x         = (const float*)d_in[0];
    const float* in_proj_w = (const float*)d_in[1];
    const float* conv_w    = (const float*)d_in[2];
    const float* conv_b    = (const float*)d_in[3];
    const float* xproj_w   = (const float*)d_in[4];
    const float* dtproj_w  = (const float*)d_in[5];
    const float* dtproj_b  = (const float*)d_in[6];
    const float* A_log     = (const float*)d_in[7];
    const float* D_p       = (const float*)d_in[8];
    const float* scale_w   = (const float*)d_in[9];
    const float* cg_w1     = (const float*)d_in[10];
    const float* cg_w2     = (const float*)d_in[11];
    const float* out_pw    = (const float*)d_in[12];
    const float* ln_gamma  = (const float*)d_in[13];
    const float* ln_beta   = (const float*)d_in[14];
    float* out = (float*)d_out;

    float* ws = (float*)d_ws;
    // f32 workspace layout (element offsets)
    float* xz    = ws;                       // 4,194,304  (2048 x 2048)
    float* xc0   = xz    + 4194304;          // xc stacked 3584x1024
    float* xc1   = xc0   + 2097152;
    float* xc2   = xc1   + 1048576;
    float* pj0   = xc2   + 524288;           // pj stacked 3584x96
    float* pj1   = pj0   + 196608;
    float* pj2   = pj1   + 98304;
    float* dt0   = pj2   + 49152;            // dt stacked 3584x1024
    float* dt1   = dt0   + 2097152;
    float* dt2   = dt1   + 1048576;
    float* y0    = dt2   + 524288;           // final y per scale (contiguous)
    float* y1    = y0    + 2097152;
    float* y2    = y1    + 1048576;
    float* hole  = y2    + 524288;           // 3,670,016-float scratch hole
    float* prodA = hole  + 3670016;          // per-chunk prodA (1,835,008)
    float* hbuf  = prodA + 1835008;          // per-chunk h -> exclusive prefix
    // f32 total: 23,887,872 floats = 95.6 MB

    // hole overlays (lifetimes disjoint by phase order):
    float* pjp   = hole;                  // xproj split-K4 partials 4x344,064
    float* h1p   = hole + 1376256;        // cg1 split-K partials 2x1,048,576
    // outp overlays prodA+hbuf (dead after P6/P7):
    float* outp  = prodA;                 // out_proj partials 2x1,048,576

    // bf16 interleaved split workspace (after f32 region; 16B-aligned)
    bf16* bws = (bf16*)(ws + 23887872);
    const bf16 *xi   = bws + OXI;
    const bf16 *ipwi = bws + OIPI;
    const bf16 *xwi  = bws + OXWI;
    const bf16 *dtwi = bws + ODTI;
    const bf16 *c1i  = bws + OC1I;
    const bf16 *c2i  = bws + OC2I;
    const bf16 *opwi = bws + OOPI;
    bf16 *pjdti = bws + OPJI;
    bf16 *fgi   = bws + OFGI;
    bf16 *ctxi  = bws + OCTXI;
    bf16 *h1i   = bws + OH1I;

    // P0) pre-split x + all weights into interleaved bf16 — 4064 blocks
    split_inputs_kernel<<<4064, 256, 0, stream>>>(
        x, in_proj_w, xproj_w, dtproj_w, cg_w1, cg_w2, out_pw, bws);

    // P1) in_proj: xz = x @ in_proj_w^T  (M=2048,N=2048,K=512) — 1024 blocks
    mgemm_kernel<0, false, false, 0, false, false><<<dim3(32, 32), 256, 0, stream>>>(
        xi, 512, 512, 512, ipwi, nullptr, nullptr, nullptr,
        nullptr, nullptr, nullptr, nullptr, nullptr, nullptr, xz, nullptr, 2048);

    // P2) fused downsample+conv+SiLU — 14336 blocks
    conv_fused_kernel<<<14336, 256, 0, stream>>>(xz, conv_w, conv_b, xc0);

    // P3) xproj stacked MFMA, SPLIT-K4 (M=3584,N=96,K=4x256) — 448 blocks
    xproj_mfma_kernel<<<dim3(56, 2, 4), 256, 0, stream>>>(xc0, xwi, pjp);

    // P3b) combine 4 partials -> pj + pre-split dt cols — 336 blocks
    combine_pj_kernel<<<336, 256, 0, stream>>>(pjp, pj0, pjdti);

    // P4) dtproj stacked (M=3584,N=1024,K=64) — 896 blocks
    mgemm_kernel<3, false, true, 0, false, false><<<dim3(56, 16), 256, 0, stream>>>(
        pjdti, 64, 64, 64, dtwi, dtproj_b, nullptr, nullptr,
        nullptr, nullptr, nullptr, nullptr, nullptr, nullptr, dt0, nullptr, 1024);

    // P5) scan pass1: per-chunk states, j-split — 896 blocks
    scan_pass1<<<896, 256, 0, stream>>>(dt0, xc0, pj0, dt1, xc1, pj1,
                                        dt2, xc2, pj2, A_log, prodA, hbuf);
    // P6) exclusive prefix over chunks (in-place on hbuf) — 384 blocks
    scan_prefix_kernel<<<384, 256, 0, stream>>>(prodA, hbuf);
    // P7) pass2: unified 16-state, final y — 448 blocks
    scan_pass2<<<448, 256, 0, stream>>>(dt0, xc0, pj0, dt1, xc1, pj1,
                                        dt2, xc2, pj2,
                                        y0, y1, y2, A_log, D_p, hbuf);

    // P7b) ctx precompute: ctxi = split((y0+up(y1)+up(y2))/3) — 2048 blocks
    ctx_kernel<<<2048, 256, 0, stream>>>(y0, y1, y2, ctxi);

    // P8) cg1, SPLIT-K2: h1p[z] = ctx @ cg_w1^T partial (pure-copy staging)
    //     (M=2048,N=512,K=2x512) — 512 blocks
    mgemm_kernel<0, false, false, 0, false, false><<<dim3(32, 8, 2), 256, 0, stream>>>(
        ctxi, 1024, 512, 1024, c1i, nullptr, nullptr, nullptr,
        nullptr, nullptr, nullptr, nullptr, nullptr, nullptr, h1p, nullptr, 512);

    // P8b) combine h1: h1i = split(silu(h1p0+h1p1)) — 1024 blocks
    combine_h1_kernel<<<1024, 256, 0, stream>>>(h1p, h1i);

    // P9) cg2 + softmax-fuse + gate (pure-copy A staging)
    //     (M=2048,N=1024,K=512) — 512 blocks
    mgemm_kernel<2, false, false, 0, true, true><<<dim3(32, 16), 256, 0, stream>>>(
        h1i, 512, 512, 512, c2i, nullptr, nullptr, xz,
        y0, y1, y2, nullptr, nullptr, scale_w, nullptr, fgi, 1024);

    // P10) out_proj + residual, SPLIT-K2 (M=2048,N=512,K=2x512) — 512 blocks
    mgemm_kernel<0, true, false, 0, false, false><<<dim3(32, 8, 2), 256, 0, stream>>>(
        fgi, 1024, 512, 1024, opwi, nullptr, x, nullptr,
        nullptr, nullptr, nullptr, nullptr, nullptr, nullptr, outp, nullptr, 512);

    // P11) LayerNorm over outp0+outp1
    ln_kernel<<<BATCH * SEQ, 256, 0, stream>>>(outp, outp + 1048576,
                                               ln_gamma, ln_beta, out);
}

// Round 8
// 269.373 us; speedup vs baseline: 1.0095x; 1.0095x over previous
//
#include <hip/hip_runtime.h>
#include <hip/hip_bf16.h>

// HierarchicalMambaBlock: B=2,T=1024,DIM=512 -> D_INNER=1024, DT_RANK=64, D_STATE=16
// GEMMs on MFMA via split precision (hi/lo bf16, 3 MFMAs: Ah*Bh + Al*Bh + Ah*Bl).
// Split operands stored INTERLEAVED: each 4-f32 group -> [hi0..hi3|lo0..lo3].
// Round-8 = round-7 + ONE change: ctx_kernel -> yfuse_kernel additionally
// emits fw = softmax(sw)-fused y (f32, sequential layout), and P9's epilogue
// reads fw once instead of 3 scattered upsample-indexed y reads (rocprof:
// P9 was 43us, FETCH 23.7MB, occupancy 19.7% -- epilogue-load latency-bound).
// Same f32 expression order -> bit-identical output.
#define BATCH   2
#define SEQ     1024
#define DIMSZ   512
#define DINNER  1024
#define DTRANK  64
#define DSTATE  16
#define CHUNK   32

typedef __hip_bfloat16 bf16;
typedef __attribute__((ext_vector_type(8))) short s8v;   // 8 bf16 MFMA frag
typedef __attribute__((ext_vector_type(4))) float f4v;   // 4 f32 acc

// Interleaved bf16 split-workspace offsets (bf16 elements, relative to bws).
constexpr size_t OXI   = 0;          // x           2048x512   -> 2,097,152
constexpr size_t OIPI  = 2097152;    // in_proj_w   2048x512   -> 2,097,152
constexpr size_t OXWI  = 4194304;    // xproj_w     3x96x1024  ->   589,824
constexpr size_t ODTI  = 4784128;    // dtproj_w    3x1024x64  ->   393,216
constexpr size_t OC1I  = 5177344;    // cg_w1       512x1024   -> 1,048,576
constexpr size_t OC2I  = 6225920;    // cg_w2       1024x512   -> 1,048,576
constexpr size_t OOPI  = 7274496;    // out_proj_w  512x1024   -> 1,048,576
constexpr size_t OPJI  = 8323072;    // pj dt-cols  3584x64    ->   458,752
constexpr size_t OFGI  = 10878976;   // fusedg      2048x1024  -> 4,194,304
constexpr size_t OCTXI = 15073280;   // ctx         2048x1024  -> 4,194,304
constexpr size_t OH1I  = 19267584;   // h1          2048x512   -> 2,097,152
// end: 21,364,736 bf16 = 42.7 MB; f32 region 95.6 MB; total ~138 MB < ws

constexpr size_t PJP_STRIDE = 344064;   // 3584 x 96 per split-K partial

__device__ __forceinline__ float sigmoidf_(float x) { return 1.f / (1.f + __expf(-x)); }
__device__ __forceinline__ float siluf_(float x) { return x * sigmoidf_(x); }
__device__ __forceinline__ void split2(float v, bf16& hi, bf16& lo) {
    hi = __float2bfloat16(v);
    lo = __float2bfloat16(v - __bfloat162float(hi));
}
// interleaved store: 4 f32 -> [hi4|lo4] (16 B) at p
__device__ __forceinline__ void split_store4i(const float4 v, bf16* __restrict__ p) {
    union { bf16 b[8]; uint4 q; } U;
    split2(v.x, U.b[0], U.b[4]); split2(v.y, U.b[1], U.b[5]);
    split2(v.z, U.b[2], U.b[6]); split2(v.w, U.b[3], U.b[7]);
    *reinterpret_cast<uint4*>(p) = U.q;
}
// LDS-stage split: 4 f32 -> separate hi/lo uint2 stores (inline-split paths)
__device__ __forceinline__ void split_store4(const float4 v,
                                             bf16* __restrict__ ph,
                                             bf16* __restrict__ pl) {
    union { bf16 b[4]; uint2 u; } H, L;
    split2(v.x, H.b[0], L.b[0]); split2(v.y, H.b[1], L.b[1]);
    split2(v.z, H.b[2], L.b[2]); split2(v.w, H.b[3], L.b[3]);
    *reinterpret_cast<uint2*>(ph) = H.u;
    *reinterpret_cast<uint2*>(pl) = L.u;
}

// ---------------------------------------------------------------------------
// Prologue: split x + all weights into persistent interleaved bf16 hi/lo.
// ---------------------------------------------------------------------------
__global__ void split_inputs_kernel(
    const float* __restrict__ x,   const float* __restrict__ ipw,
    const float* __restrict__ xw,  const float* __restrict__ dtw,
    const float* __restrict__ c1,  const float* __restrict__ c2,
    const float* __restrict__ opw, bf16* __restrict__ bws)
{
    int blk = blockIdx.x;
    const float* src; size_t off;
    if (blk < 1024)      { src = x;   off = OXI;  }
    else if (blk < 2048) { src = ipw; off = OIPI; blk -= 1024; }
    else if (blk < 2336) { src = xw;  off = OXWI; blk -= 2048; }
    else if (blk < 2528) { src = dtw; off = ODTI; blk -= 2336; }
    else if (blk < 3040) { src = c1;  off = OC1I; blk -= 2528; }
    else if (blk < 3552) { src = c2;  off = OC2I; blk -= 3040; }
    else                 { src = opw; off = OOPI; blk -= 3552; }
    int i = blk * 1024 + threadIdx.x * 4;
    float4 v = *reinterpret_cast<const float4*>(src + i);
    split_store4i(v, bws + off + (size_t)i * 2);
}

// ---------------------------------------------------------------------------
// MFMA GEMM, 64x64 tile, BK=64, 4 waves, register prefetch, optional SPLIT-K
// via gridDim.z (each z-block covers K cols [z*K, z*K+K) and writes its own
// C partial at z * gridDim.x*64 * N).
// AMODE: 0 = interleaved pre-split A (pure-copy staging)
// ACT: 0 none, 1 silu, 2 sigmoid, 3 bias+softplus
// DT_MODE: stacked dtproj: per-block W/bias select by scale
// GATEF:   v = fw[gm*N+gn] * v * silu(xz gate)   (fw precomputed fused y)
// OUT_SPLIT: write interleaved hi/lo bf16 (Ci) instead of f32 C.
// ---------------------------------------------------------------------------
template <int ACT, bool ADD_RES, bool DT_MODE, int AMODE, bool GATEF, bool OUT_SPLIT>
__global__ __launch_bounds__(256) void mgemm_kernel(
    const bf16* __restrict__ Ai, int lda, int K, int ldb,
    const bf16* __restrict__ Bi,
    const float* __restrict__ bias,
    const float* __restrict__ res,          // residual (ADD_RES, z==0 only)
    const float* __restrict__ gxz,          // xz (GATEF)
    const float* __restrict__ fw,           // GATEF fused y (f32, ld = N)
    float* __restrict__ C, bf16* __restrict__ Ci, int N)
{
    __shared__ bf16 Ah[64][72], Al[64][72], Bh[64][72], Bl[64][72];

    const int m0 = blockIdx.x * 64;
    const int n0 = blockIdx.y * 64;
    const int kz = blockIdx.z;
    const int koff = kz * K;
    const size_t coff = (size_t)kz * (size_t)(gridDim.x * 64) * N;
    const int tid = threadIdx.x;
    const int wave = tid >> 6;
    const int lane = tid & 63;
    const int wm = (wave >> 1) * 32;
    const int wn = (wave & 1) * 32;
    const int m16 = lane & 15;
    const int q   = lane >> 4;

    int scale = 0;
    if (DT_MODE) scale = (m0 < 2048) ? 0 : ((m0 < 3072) ? 1 : 2);
    const bf16* Bip = DT_MODE ? (Bi + (size_t)scale * 1024 * ldb * 2) : Bi;
    const float* bias_p = (ACT == 3) ? (DT_MODE ? bias + (size_t)scale * N : bias) : nullptr;

    f4v acc[2][2];
#pragma unroll
    for (int i = 0; i < 2; i++)
#pragma unroll
        for (int j = 0; j < 2; j++)
#pragma unroll
            for (int r = 0; r < 4; r++) acc[i][j][r] = 0.f;

    const int cch = tid & 15;
    const int c4  = cch * 4;
    const int r0  = tid >> 4;

    // A row pointers (interleaved pre-split)
    const bf16* aip[4];
#pragma unroll
    for (int p = 0; p < 4; p++) {
        int m = m0 + r0 + p * 16;
        aip[p] = Ai + ((size_t)m * lda + koff + c4) * 2;
    }
    const bf16* Bi_b = Bip + ((size_t)(n0 + r0) * ldb + koff + c4) * 2;

    const int nkt = K >> 6;
    uint2 rah[4], ral[4], rbh[4], rbl[4];
#pragma unroll
    for (int p = 0; p < 4; p++) {
        uint4 ua = *reinterpret_cast<const uint4*>(aip[p]);
        rah[p] = make_uint2(ua.x, ua.y); ral[p] = make_uint2(ua.z, ua.w);
        uint4 ub = *reinterpret_cast<const uint4*>(Bi_b + (size_t)(p * 16) * ldb * 2);
        rbh[p] = make_uint2(ub.x, ub.y); rbl[p] = make_uint2(ub.z, ub.w);
    }

    for (int kt = 0; kt < nkt; kt++) {
        if (kt) __syncthreads();
#pragma unroll
        for (int p = 0; p < 4; p++) {
            int r = r0 + p * 16;
            *reinterpret_cast<uint2*>(&Ah[r][c4]) = rah[p];
            *reinterpret_cast<uint2*>(&Al[r][c4]) = ral[p];
            *reinterpret_cast<uint2*>(&Bh[r][c4]) = rbh[p];
            *reinterpret_cast<uint2*>(&Bl[r][c4]) = rbl[p];
        }
        __syncthreads();
        if (kt + 1 < nkt) {
            int off = (kt + 1) * 64;
#pragma unroll
            for (int p = 0; p < 4; p++) {
                uint4 ua = *reinterpret_cast<const uint4*>(aip[p] + (size_t)off * 2);
                rah[p] = make_uint2(ua.x, ua.y); ral[p] = make_uint2(ua.z, ua.w);
                uint4 ub = *reinterpret_cast<const uint4*>(Bi_b + ((size_t)(p * 16) * ldb + off) * 2);
                rbh[p] = make_uint2(ub.x, ub.y); rbl[p] = make_uint2(ub.z, ub.w);
            }
        }
#pragma unroll
        for (int kk = 0; kk < 2; kk++) {
            const int col = kk * 32 + q * 8;
            s8v ah[2], al[2], bh[2], bl[2];
#pragma unroll
            for (int i = 0; i < 2; i++) {
                int ar = wm + i * 16 + m16;
                ah[i] = *reinterpret_cast<const s8v*>(&Ah[ar][col]);
                al[i] = *reinterpret_cast<const s8v*>(&Al[ar][col]);
                int br = wn + i * 16 + m16;
                bh[i] = *reinterpret_cast<const s8v*>(&Bh[br][col]);
                bl[i] = *reinterpret_cast<const s8v*>(&Bl[br][col]);
            }
#pragma unroll
            for (int i = 0; i < 2; i++)
#pragma unroll
                for (int j = 0; j < 2; j++) {
                    acc[i][j] = __builtin_amdgcn_mfma_f32_16x16x32_bf16(ah[i], bh[j], acc[i][j], 0, 0, 0);
                    acc[i][j] = __builtin_amdgcn_mfma_f32_16x16x32_bf16(al[i], bh[j], acc[i][j], 0, 0, 0);
                    acc[i][j] = __builtin_amdgcn_mfma_f32_16x16x32_bf16(ah[i], bl[j], acc[i][j], 0, 0, 0);
                }
        }
    }

    // Epilogue. D mapping (verified): row = q*4 + reg, col = lane&15.
#pragma unroll
    for (int i = 0; i < 2; i++) {
#pragma unroll
        for (int j = 0; j < 2; j++) {
#pragma unroll
            for (int r = 0; r < 4; r++) {
                int gm = m0 + wm + i * 16 + q * 4 + r;
                int gn = n0 + wn + j * 16 + m16;
                float v = acc[i][j][r];
                if (ACT == 3) { v += bias_p[gn]; v = (v > 20.f) ? v : __logf(1.f + __expf(v)); }
                else if (ACT == 1) v = siluf_(v);
                else if (ACT == 2) v = sigmoidf_(v);
                if (GATEF) {
                    float f = fw[(size_t)gm * N + gn];
                    v = f * v * siluf_(gxz[(size_t)gm * 2048 + 1024 + gn]);
                } else if (ADD_RES) {
                    if (kz == 0) v += res[(size_t)gm * N + gn];
                }
                if (OUT_SPLIT) {
                    bf16 hh, ll; split2(v, hh, ll);
                    size_t gb = ((size_t)gm * N + (gn & ~3)) * 2 + (gn & 3);
                    Ci[gb] = hh;
                    Ci[gb + 4] = ll;
                } else {
                    C[coff + (size_t)gm * N + gn] = v;
                }
            }
        }
    }
}

// ---------------------------------------------------------------------------
// xproj MFMA: stacked M=3584, N=96 (clamped), K=1024 SPLIT-K4 (z in {0..3},
// 256 cols each). Grid (56,2,4) = 448 blocks. Writes f32 partial pjp[z].
// ---------------------------------------------------------------------------
__global__ __launch_bounds__(256) void xproj_mfma_kernel(
    const float* __restrict__ A,
    const bf16* __restrict__ xwi,
    float* __restrict__ pjp)
{
    __shared__ bf16 Ah[64][72], Al[64][72], Bh[64][72], Bl[64][72];

    const int m0 = blockIdx.x * 64;
    const int n0 = blockIdx.y * 64;
    const int kz = blockIdx.z;
    const int koff = kz * 256;
    const int tid = threadIdx.x;
    const int wave = tid >> 6;
    const int lane = tid & 63;
    const int wm = (wave >> 1) * 32;
    const int wn = (wave & 1) * 32;
    const int m16 = lane & 15;
    const int q   = lane >> 4;

    const int scale = (m0 < 2048) ? 0 : ((m0 < 3072) ? 1 : 2);
    const bf16* Bip = xwi + (size_t)scale * 96 * 1024 * 2;

    f4v acc[2][2];
#pragma unroll
    for (int i = 0; i < 2; i++)
#pragma unroll
        for (int j = 0; j < 2; j++)
#pragma unroll
            for (int r = 0; r < 4; r++) acc[i][j][r] = 0.f;

    const int cch = tid & 15;
    const int c4  = cch * 4;
    const int r0  = tid >> 4;

    const float* Abase = A + (size_t)(m0 + r0) * 1024 + koff + c4;
    const bf16* Bi_b = Bip + ((size_t)(n0 + r0) * 1024 + koff + c4) * 2;
    bool bok[4];
#pragma unroll
    for (int p = 0; p < 4; p++) bok[p] = (n0 + r0 + p * 16) < 96;

    const int nkt = 4;   // 256 / 64
    float4 ra[4]; uint2 rbh[4], rbl[4];
#pragma unroll
    for (int p = 0; p < 4; p++) {
        ra[p] = *reinterpret_cast<const float4*>(Abase + (size_t)(p * 16) * 1024);
        if (bok[p]) {
            uint4 ub = *reinterpret_cast<const uint4*>(Bi_b + (size_t)(p * 16) * 1024 * 2);
            rbh[p] = make_uint2(ub.x, ub.y); rbl[p] = make_uint2(ub.z, ub.w);
        } else { rbh[p] = make_uint2(0u, 0u); rbl[p] = make_uint2(0u, 0u); }
    }

    for (int kt = 0; kt < nkt; kt++) {
        if (kt) __syncthreads();
#pragma unroll
        for (int p = 0; p < 4; p++) {
            int r = r0 + p * 16;
            split_store4(ra[p], &Ah[r][c4], &Al[r][c4]);
            *reinterpret_cast<uint2*>(&Bh[r][c4]) = rbh[p];
            *reinterpret_cast<uint2*>(&Bl[r][c4]) = rbl[p];
        }
        __syncthreads();
        if (kt + 1 < nkt) {
            int off = (kt + 1) * 64;
#pragma unroll
            for (int p = 0; p < 4; p++) {
                ra[p] = *reinterpret_cast<const float4*>(Abase + off + (size_t)(p * 16) * 1024);
                if (bok[p]) {
                    uint4 ub = *reinterpret_cast<const uint4*>(Bi_b + ((size_t)(p * 16) * 1024 + off) * 2);
                    rbh[p] = make_uint2(ub.x, ub.y); rbl[p] = make_uint2(ub.z, ub.w);
                }
            }
        }
#pragma unroll
        for (int kk = 0; kk < 2; kk++) {
            const int col = kk * 32 + q * 8;
            s8v ah[2], al[2], bh[2], bl[2];
#pragma unroll
            for (int i = 0; i < 2; i++) {
                int ar = wm + i * 16 + m16;
                ah[i] = *reinterpret_cast<const s8v*>(&Ah[ar][col]);
                al[i] = *reinterpret_cast<const s8v*>(&Al[ar][col]);
                int br = wn + i * 16 + m16;
                bh[i] = *reinterpret_cast<const s8v*>(&Bh[br][col]);
                bl[i] = *reinterpret_cast<const s8v*>(&Bl[br][col]);
            }
#pragma unroll
            for (int i = 0; i < 2; i++)
#pragma unroll
                for (int j = 0; j < 2; j++) {
                    acc[i][j] = __builtin_amdgcn_mfma_f32_16x16x32_bf16(ah[i], bh[j], acc[i][j], 0, 0, 0);
                    acc[i][j] = __builtin_amdgcn_mfma_f32_16x16x32_bf16(al[i], bh[j], acc[i][j], 0, 0, 0);
                    acc[i][j] = __builtin_amdgcn_mfma_f32_16x16x32_bf16(ah[i], bl[j], acc[i][j], 0, 0, 0);
                }
        }
    }

    float* out = pjp + (size_t)kz * PJP_STRIDE;
#pragma unroll
    for (int i = 0; i < 2; i++) {
#pragma unroll
        for (int j = 0; j < 2; j++) {
            int gn = n0 + wn + j * 16 + m16;
            if (gn >= 96) continue;
#pragma unroll
            for (int r = 0; r < 4; r++) {
                int gm = m0 + wm + i * 16 + q * 4 + r;
                out[(size_t)gm * 96 + gn] = acc[i][j][r];
            }
        }
    }
}

// ---------------------------------------------------------------------------
// combine_pj: pj = pjp0+pjp1+pjp2+pjp3 (3584x96); dt cols (gn<64) also
// emitted as interleaved split for dtproj. 336 blocks x 256 threads x 4.
// ---------------------------------------------------------------------------
__global__ void combine_pj_kernel(const float* __restrict__ pjp,
                                  float* __restrict__ pj,
                                  bf16* __restrict__ pjdti)
{
    int g = blockIdx.x * 256 + threadIdx.x;   // 86016 float4 groups
    if (g >= 86016) return;
    int gm = g / 24;
    int gc = (g % 24) * 4;
    size_t o = (size_t)gm * 96 + gc;
    float4 a = *reinterpret_cast<const float4*>(pjp + o);
    float4 b = *reinterpret_cast<const float4*>(pjp + PJP_STRIDE + o);
    float4 c = *reinterpret_cast<const float4*>(pjp + 2 * PJP_STRIDE + o);
    float4 d = *reinterpret_cast<const float4*>(pjp + 3 * PJP_STRIDE + o);
    float4 s = make_float4(a.x + b.x + c.x + d.x, a.y + b.y + c.y + d.y,
                           a.z + b.z + c.z + d.z, a.w + b.w + c.w + d.w);
    *reinterpret_cast<float4*>(pj + o) = s;
    if (gc < 64) split_store4i(s, pjdti + ((size_t)gm * 64 + gc) * 2);
}

// ---------------------------------------------------------------------------
// yfuse: ctxi = split((y0 + up(y1) + up(y2)) / 3) AND fw = softmax(sw)-fused y
// (f32, sequential). 2048 blocks x 256 x 4 elems. Same f32 expression order
// as the old inline paths -> bit-identical.
// ---------------------------------------------------------------------------
__global__ void yfuse_kernel(const float* __restrict__ y0,
                             const float* __restrict__ y1,
                             const float* __restrict__ y2,
                             const float* __restrict__ swp,
                             bf16* __restrict__ ctxi,
                             float* __restrict__ fw)
{
    int g = blockIdx.x * 256 + threadIdx.x;   // 524,288 float4 groups
    int m = g >> 8;
    int k = (g & 255) << 2;
    int b = m >> 10, t = m & 1023;
    float4 u = *reinterpret_cast<const float4*>(y0 + (size_t)m * 1024 + k);
    float4 v = *reinterpret_cast<const float4*>(y1 + (size_t)((b << 9) + (t >> 1)) * 1024 + k);
    float4 w = *reinterpret_cast<const float4*>(y2 + (size_t)((b << 8) + (t >> 2)) * 1024 + k);
    float4 c = make_float4((u.x + v.x + w.x) * (1.f / 3.f), (u.y + v.y + w.y) * (1.f / 3.f),
                           (u.z + v.z + w.z) * (1.f / 3.f), (u.w + v.w + w.w) * (1.f / 3.f));
    split_store4i(c, ctxi + ((size_t)m * 1024 + k) * 2);

    float s0 = swp[0], s1 = swp[1], s2 = swp[2];
    float mx = fmaxf(s0, fmaxf(s1, s2));
    float e0 = __expf(s0 - mx), e1 = __expf(s1 - mx), e2 = __expf(s2 - mx);
    float inv = 1.f / (e0 + e1 + e2);
    float4 f = make_float4((e0 * u.x + e1 * v.x + e2 * w.x) * inv,
                           (e0 * u.y + e1 * v.y + e2 * w.y) * inv,
                           (e0 * u.z + e1 * v.z + e2 * w.z) * inv,
                           (e0 * u.w + e1 * v.w + e2 * w.w) * inv);
    *reinterpret_cast<float4*>(fw + (size_t)m * 1024 + k) = f;
}

// ---------------------------------------------------------------------------
// combine_h1: h1i = split(silu(h1p0 + h1p1)). 1024 blocks x 256 x 4 elems.
// ---------------------------------------------------------------------------
__global__ void combine_h1_kernel(const float* __restrict__ h1p,
                                  bf16* __restrict__ h1i)
{
    int g = blockIdx.x * 256 + threadIdx.x;   // 262,144 float4 groups
    size_t o = (size_t)g * 4;
    float4 u = *reinterpret_cast<const float4*>(h1p + o);
    float4 v = *reinterpret_cast<const float4*>(h1p + 1048576 + o);
    float4 s = make_float4(siluf_(u.x + v.x), siluf_(u.y + v.y),
                           siluf_(u.z + v.z), siluf_(u.w + v.w));
    split_store4i(s, h1i + o * 2);
}

// ---------------------------------------------------------------------------
// Fused downsample + depthwise causal conv(K=4) + bias + SiLU, all 3 scales.
// ---------------------------------------------------------------------------
__global__ void conv_fused_kernel(const float* __restrict__ xz,
                                  const float* __restrict__ cw,
                                  const float* __restrict__ cb,
                                  float* __restrict__ xc)
{
    int idx = blockIdx.x * blockDim.x + threadIdx.x;
    if (idx >= 3670016) return;
    int s, rel;
    if (idx < 2097152)      { s = 0; rel = idx; }
    else if (idx < 3145728) { s = 1; rel = idx - 2097152; }
    else                    { s = 2; rel = idx - 3145728; }
    int c = rel & 1023;
    int row = rel >> 10;
    int Ts = 1024 >> s;
    int b = row / Ts;
    int t = row - b * Ts;
    const float* base = xz + (size_t)(b * 1024) * 2048 + c;

    float acc = cb[s * 1024 + c];
#pragma unroll
    for (int k = 0; k < 4; k++) {
        int tau = t - 3 + k;
        if (tau < 0) continue;
        float xv;
        if (s == 0) {
            xv = base[(size_t)tau * 2048];
        } else if (s == 1) {
            xv = 0.5f * (base[(size_t)(2 * tau) * 2048] + base[(size_t)(2 * tau + 1) * 2048]);
        } else {
            xv = 0.25f * (base[(size_t)(4 * tau) * 2048] + base[(size_t)(4 * tau + 1) * 2048]
                        + base[(size_t)(4 * tau + 2) * 2048] + base[(size_t)(4 * tau + 3) * 2048]);
        }
        acc = fmaf(cw[(s * 1024 + c) * 4 + k], xv, acc);
    }
    xc[idx] = siluf_(acc);
}

// ---------------------------------------------------------------------------
// Chunked selective scan. State layout: [s][b][chunk][j][d] (d fastest).
// ---------------------------------------------------------------------------
__device__ __forceinline__ void scan_decode(int blk, int& s, int& nchunk, int& Ts,
                                            int& dquad, int& chunk, int& b, size_t& soff)
{
    int local;
    if (blk < 256)      { s = 0; local = blk;       soff = 0; }
    else if (blk < 384) { s = 1; local = blk - 256; soff = 1048576; }
    else                { s = 2; local = blk - 384; soff = 1572864; }
    nchunk = 32 >> s;
    Ts = 1024 >> s;
    dquad = local & 3;
    chunk = (local >> 2) & (nchunk - 1);
    b = local >> (7 - s);
}

// pass1: per-chunk (prodA, h) states; j-split (8 states/block), 896 blocks.
__global__ __launch_bounds__(256) void scan_pass1(
    const float* __restrict__ dt0, const float* __restrict__ xc0, const float* __restrict__ pj0,
    const float* __restrict__ dt1, const float* __restrict__ xc1, const float* __restrict__ pj1,
    const float* __restrict__ dt2, const float* __restrict__ xc2, const float* __restrict__ pj2,
    const float* __restrict__ A_log,
    float* __restrict__ prodA_buf, float* __restrict__ h_buf)
{
    const int jhalf = (blockIdx.x >= 448) ? 1 : 0;
    const int jo = jhalf * 8;
    int s, nchunk, Ts, dquad, chunk, b; size_t soff;
    scan_decode(blockIdx.x - jhalf * 448, s, nchunk, Ts, dquad, chunk, b, soff);
    const float* dt = (s == 0) ? dt0 : (s == 1) ? dt1 : dt2;
    const float* xc = (s == 0) ? xc0 : (s == 1) ? xc1 : xc2;
    const float* pj = (s == 0) ? pj0 : (s == 1) ? pj1 : pj2;

    const int d = dquad * 256 + threadIdx.x;
    const size_t rowbase = (size_t)b * Ts;
    const int t0 = chunk * CHUNK;

    float Acoef[8], h[8], p[8];
#pragma unroll
    for (int j = 0; j < 8; j++) {
        Acoef[j] = -__expf(A_log[((size_t)(s * DINNER + d)) * 16 + jo + j]);
        h[j] = 0.f; p[j] = 1.f;
    }

    __shared__ float bcB[CHUNK][8];
    if (threadIdx.x < CHUNK * 8) {
        int i = threadIdx.x >> 3, jj = threadIdx.x & 7;
        bcB[i][jj] = pj[(rowbase + t0 + i) * 96 + 64 + jo + jj];
    }
    __syncthreads();

    for (int i = 0; i < CHUNK; i++) {
        size_t t = rowbase + t0 + i;
        float dtv = dt[t * DINNER + d];
        float xv  = xc[t * DINNER + d];
#pragma unroll
        for (int j = 0; j < 8; j++) {
            float dA  = fmaxf(__expf(dtv * Acoef[j]), 1e-38f);
            float dbx = fmaxf(dtv * bcB[i][j] * xv, 1e-38f);
            h[j] = fmaf(dA, h[j], dbx);
            p[j] *= dA;
        }
    }

    size_t base = soff + (size_t)((b * nchunk + chunk) * 16 + jo) * 1024 + d;
#pragma unroll
    for (int j = 0; j < 8; j++) {
        prodA_buf[base + (size_t)j * 1024] = p[j];
        h_buf[base + (size_t)j * 1024] = h[j];
    }
}

// scan_prefix: in-place exclusive prefix over chunks: h_buf[c] <- H_excl(c).
__global__ __launch_bounds__(256) void scan_prefix_kernel(
    const float* __restrict__ prodA_buf, float* __restrict__ h_buf)
{
    int blk = blockIdx.x;
    int s; size_t soff;
    if (blk < 128)      { s = 0; soff = 0; }
    else if (blk < 256) { s = 1; soff = 1048576; blk -= 128; }
    else                { s = 2; soff = 1572864; blk -= 256; }
    const int nchunk = 32 >> s;
    const int b  = blk >> 6;          // local = b*64 + j*4 + dq
    const int j  = (blk >> 2) & 15;
    const int dq = blk & 3;
    const int d  = dq * 256 + threadIdx.x;

    float H = 0.f;
    for (int c = 0; c < nchunk; c++) {
        size_t idx = soff + (size_t)((b * nchunk + c) * 16 + j) * 1024 + d;
        float p = prodA_buf[idx];
        float h = h_buf[idx];
        h_buf[idx] = H;
        H = fmaf(p, H, h);
    }
}

// pass2: unified 16-state, O(1) carry, writes final y directly. 448 blocks.
__global__ __launch_bounds__(256) void scan_pass2(
    const float* __restrict__ dt0, const float* __restrict__ xc0,
    const float* __restrict__ pj0,
    const float* __restrict__ dt1, const float* __restrict__ xc1,
    const float* __restrict__ pj1,
    const float* __restrict__ dt2, const float* __restrict__ xc2,
    const float* __restrict__ pj2,
    float* __restrict__ y0, float* __restrict__ y1, float* __restrict__ y2,
    const float* __restrict__ A_log, const float* __restrict__ D_p,
    const float* __restrict__ carry)
{
    int s, nchunk, Ts, dquad, chunk, b; size_t soff;
    scan_decode(blockIdx.x, s, nchunk, Ts, dquad, chunk, b, soff);
    const float* dt = (s == 0) ? dt0 : (s == 1) ? dt1 : dt2;
    const float* xc = (s == 0) ? xc0 : (s == 1) ? xc1 : xc2;
    const float* pj = (s == 0) ? pj0 : (s == 1) ? pj1 : pj2;
    float* y = (s == 0) ? y0 : (s == 1) ? y1 : y2;

    const int d = dquad * 256 + threadIdx.x;
    const size_t rowbase = (size_t)b * Ts;
    const int t0 = chunk * CHUNK;

    float Acoef[16], h[16];
    const size_t cb = soff + (size_t)((b * nchunk + chunk) * 16) * 1024 + d;
#pragma unroll
    for (int j = 0; j < 16; j++) {
        Acoef[j] = -__expf(A_log[((size_t)(s * DINNER + d)) * 16 + j]);
        h[j] = carry[cb + (size_t)j * 1024];
    }
    const float Dp = D_p[s * DINNER + d];

    __shared__ float bc[CHUNK][32];   // B (0..15) and C (16..31)
    for (int u = threadIdx.x; u < CHUNK * 32; u += 256) {
        int i = u >> 5, jj = u & 31;
        bc[i][jj] = pj[(rowbase + t0 + i) * 96 + 64 + jj];
    }
    __syncthreads();

    for (int i = 0; i < CHUNK; i++) {
        size_t t = rowbase + t0 + i;
        float dtv = dt[t * DINNER + d];
        float xv  = xc[t * DINNER + d];
        float accy = 0.f;
#pragma unroll
        for (int j = 0; j < 16; j++) {
            float dA  = fmaxf(__expf(dtv * Acoef[j]), 1e-38f);
            float dbx = fmaxf(dtv * bc[i][j] * xv, 1e-38f);
            h[j] = fmaf(dA, h[j], dbx);
            accy = fmaf(bc[i][16 + j], h[j], accy);
        }
        y[t * DINNER + d] = accy + Dp * xv;
    }
}

// ---------------------------------------------------------------------------
// LayerNorm over outp0+outp1 (split-K partials of out_proj).
// ---------------------------------------------------------------------------
__global__ __launch_bounds__(256) void ln_kernel(
    const float* __restrict__ ya, const float* __restrict__ yb,
    const float* __restrict__ gamma,
    const float* __restrict__ beta, float* __restrict__ out)
{
    int token = blockIdx.x;
    int tid = threadIdx.x;
    size_t o = (size_t)token * DIMSZ;
    float v0 = ya[o + tid] + yb[o + tid];
    float v1 = ya[o + tid + 256] + yb[o + tid + 256];
    __shared__ float s1[256], s2[256];
    s1[tid] = v0 + v1;
    s2[tid] = v0 * v0 + v1 * v1;
    __syncthreads();
    for (int off = 128; off > 0; off >>= 1) {
        if (tid < off) { s1[tid] += s1[tid + off]; s2[tid] += s2[tid + off]; }
        __syncthreads();
    }
    float mu = s1[0] * (1.f / 512.f);
    float var = s2[0] * (1.f / 512.f) - mu * mu;
    float rstd = rsqrtf(var + 1e-5f);
    float* orow = out + o;
    orow[tid]       = (v0 - mu) * rstd * gamma[tid]       + beta[tid];
    orow[tid + 256] = (v1 - mu) * rstd * gamma[tid + 256] + beta[tid + 256];
}

// ---------------------------------------------------------------------------
extern "C" void kernel_launch(void* const* d_in, const int* in_sizes, int n_in,
                              void* d_out, int out_size, void* d_ws, size_t ws_size,
                              hipStream_t stream)
{
    const float* x         = (const float*)d_in[0];
    const float* in_proj_w = (const float*)d_in[1];
    const float* conv_w    = (const float*)d_in[2];
    const float* conv_b    = (const float*)d_in[3];
    const float* xproj_w   = (const float*)d_in[4];
    const float* dtproj_w  = (const float*)d_in[5];
    const float* dtproj_b  = (const float*)d_in[6];
    const float* A_log     = (const float*)d_in[7];
    const float* D_p       = (const float*)d_in[8];
    const float* scale_w   = (const float*)d_in[9];
    const float* cg_w1     = (const float*)d_in[10];
    const float* cg_w2     = (const float*)d_in[11];
    const float* out_pw    = (const float*)d_in[12];
    const float* ln_gamma  = (const float*)d_in[13];
    const float* ln_beta   = (const float*)d_in[14];
    float* out = (float*)d_out;

    float* ws = (float*)d_ws;
    // f32 workspace layout (element offsets)
    float* xz    = ws;                       // 4,194,304  (2048 x 2048)
    float* xc0   = xz    + 4194304;          // xc stacked 3584x1024
    float* xc1   = xc0   + 2097152;
    float* xc2   = xc1   + 1048576;
    float* pj0   = xc2   + 524288;           // pj stacked 3584x96
    float* pj1   = pj0   + 196608;
    float* pj2   = pj1   + 98304;
    float* dt0   = pj2   + 49152;            // dt stacked 3584x1024
    float* dt1   = dt0   + 2097152;
    float* dt2   = dt1   + 1048576;
    float* y0    = dt2   + 524288;           // final y per scale (contiguous)
    float* y1    = y0    + 2097152;
    float* y2    = y1    + 1048576;
    float* hole  = y2    + 524288;           // 3,670,016-float scratch hole
    float* prodA = hole  + 3670016;          // per-chunk prodA (1,835,008)
    float* hbuf  = prodA + 1835008;          // per-chunk h -> exclusive prefix
    // f32 total: 23,887,872 floats = 95.6 MB

    // hole overlays (lifetimes disjoint by phase order):
    float* pjp   = hole;                  // xproj split-K4 partials 4x344,064
    float* h1p   = hole + 1376256;        // cg1 split-K partials 2x1,048,576
    // overlays on prodA+hbuf (dead after P6/P7):
    float* fw    = prodA;                 // yfuse fused y (2,097,152)
    float* outp  = prodA;                 // out_proj partials (after P9 read fw)

    // bf16 interleaved split workspace (after f32 region; 16B-aligned)
    bf16* bws = (bf16*)(ws + 23887872);
    const bf16 *xi   = bws + OXI;
    const bf16 *ipwi = bws + OIPI;
    const bf16 *xwi  = bws + OXWI;
    const bf16 *dtwi = bws + ODTI;
    const bf16 *c1i  = bws + OC1I;
    const bf16 *c2i  = bws + OC2I;
    const bf16 *opwi = bws + OOPI;
    bf16 *pjdti = bws + OPJI;
    bf16 *fgi   = bws + OFGI;
    bf16 *ctxi  = bws + OCTXI;
    bf16 *h1i   = bws + OH1I;

    // P0) pre-split x + all weights into interleaved bf16 — 4064 blocks
    split_inputs_kernel<<<4064, 256, 0, stream>>>(
        x, in_proj_w, xproj_w, dtproj_w, cg_w1, cg_w2, out_pw, bws);

    // P1) in_proj: xz = x @ in_proj_w^T  (M=2048,N=2048,K=512) — 1024 blocks
    mgemm_kernel<0, false, false, 0, false, false><<<dim3(32, 32), 256, 0, stream>>>(
        xi, 512, 512, 512, ipwi, nullptr, nullptr, nullptr, nullptr,
        xz, nullptr, 2048);

    // P2) fused downsample+conv+SiLU — 14336 blocks
    conv_fused_kernel<<<14336, 256, 0, stream>>>(xz, conv_w, conv_b, xc0);

    // P3) xproj stacked MFMA, SPLIT-K4 (M=3584,N=96,K=4x256) — 448 blocks
    xproj_mfma_kernel<<<dim3(56, 2, 4), 256, 0, stream>>>(xc0, xwi, pjp);

    // P3b) combine 4 partials -> pj + pre-split dt cols — 336 blocks
    combine_pj_kernel<<<336, 256, 0, stream>>>(pjp, pj0, pjdti);

    // P4) dtproj stacked (M=3584,N=1024,K=64) — 896 blocks
    mgemm_kernel<3, false, true, 0, false, false><<<dim3(56, 16), 256, 0, stream>>>(
        pjdti, 64, 64, 64, dtwi, dtproj_b, nullptr, nullptr, nullptr,
        dt0, nullptr, 1024);

    // P5) scan pass1: per-chunk states, j-split — 896 blocks
    scan_pass1<<<896, 256, 0, stream>>>(dt0, xc0, pj0, dt1, xc1, pj1,
                                        dt2, xc2, pj2, A_log, prodA, hbuf);
    // P6) exclusive prefix over chunks (in-place on hbuf) — 384 blocks
    scan_prefix_kernel<<<384, 256, 0, stream>>>(prodA, hbuf);
    // P7) pass2: unified 16-state, final y — 448 blocks
    scan_pass2<<<448, 256, 0, stream>>>(dt0, xc0, pj0, dt1, xc1, pj1,
                                        dt2, xc2, pj2,
                                        y0, y1, y2, A_log, D_p, hbuf);

    // P7b) yfuse: ctxi = split(ctx) AND fw = softmax-fused y — 2048 blocks
    yfuse_kernel<<<2048, 256, 0, stream>>>(y0, y1, y2, scale_w, ctxi, fw);

    // P8) cg1, SPLIT-K2: h1p[z] = ctx @ cg_w1^T partial (pure-copy staging)
    //     (M=2048,N=512,K=2x512) — 512 blocks
    mgemm_kernel<0, false, false, 0, false, false><<<dim3(32, 8, 2), 256, 0, stream>>>(
        ctxi, 1024, 512, 1024, c1i, nullptr, nullptr, nullptr, nullptr,
        h1p, nullptr, 512);

    // P8b) combine h1: h1i = split(silu(h1p0+h1p1)) — 1024 blocks
    combine_h1_kernel<<<1024, 256, 0, stream>>>(h1p, h1i);

    // P9) cg2 + fw-gate: fusedg = fw * sigmoid(h1 @ cg_w2^T) * silu(gate)
    //     (M=2048,N=1024,K=512) — 512 blocks
    mgemm_kernel<2, false, false, 0, true, true><<<dim3(32, 16), 256, 0, stream>>>(
        h1i, 512, 512, 512, c2i, nullptr, nullptr, xz, fw,
        nullptr, fgi, 1024);

    // P10) out_proj + residual, SPLIT-K2 (M=2048,N=512,K=2x512) — 512 blocks
    mgemm_kernel<0, true, false, 0, false, false><<<dim3(32, 8, 2), 256, 0, stream>>>(
        fgi, 1024, 512, 1024, opwi, nullptr, x, nullptr, nullptr,
        outp, nullptr, 512);

    // P11) LayerNorm over outp0+outp1
    ln_kernel<<<BATCH * SEQ, 256, 0, stream>>>(outp, outp + 1048576,
                                               ln_gamma, ln_beta, out);
}